// Round 1
// baseline (259.165 us; speedup 1.0000x reference)
//
#include <hip/hip_runtime.h>

#define TEX_H 256
#define TEX_W 256
#define FCH 16
#define NPIX (8 * 256 * 256)
#define NTEX (TEX_H * TEX_W)

// DECAY = sqrt(2 * 0.5^2) = sqrt(0.5)
#define DECAY_F 0.7071067811865476f

// Splat: 16 threads per pixel (one per channel). Lane group of 16 shares one
// pixel; feature reads are fully coalesced (64 consecutive floats per wave).
// Each contribution (window slot passing threshold+valid) costs 1 atomic per
// channel-lane + 1 wsum atomic on lane c==0.
__global__ __launch_bounds__(256) void splat_kernel(
    const float* __restrict__ f_map,
    const float* __restrict__ uv_map,
    const float* __restrict__ mask,
    float* __restrict__ wsum,
    float* __restrict__ csum)
{
    int tid = blockIdx.x * 256 + threadIdx.x;
    int pix = tid >> 4;
    int c   = tid & 15;
    if (pix >= NPIX) return;

    float m = mask[pix];
    if (m == 0.0f) return;   // masked-out pixel contributes nothing

    float u = uv_map[pix * 2 + 0] * (float)TEX_W;
    float v = uv_map[pix * 2 + 1] * (float)TEX_H;
    float f = f_map[pix * FCH + c];

    float us = fmaxf(u - 2.0f, 0.0f);
    float vs = fmaxf(v - 2.0f, 0.0f);

    #pragma unroll
    for (int kv = 0; kv < 4; ++kv) {
        float vg = vs + (float)kv;
        int   vi = (int)vg;                 // vg >= 0, trunc == floor
        float dv = fabsf(vg - v);
        dv = fminf(dv, fabsf(dv - (float)TEX_H));   // wrap distance (ref exact)
        #pragma unroll
        for (int ku = 0; ku < 4; ++ku) {
            float ug = us + (float)ku;
            int   ui = (int)ug;
            float du = fabsf(ug - u);
            du = fminf(du, fabsf(du - (float)TEX_W));
            float w = expf(-sqrtf(du * du + dv * dv) / DECAY_F);
            // ref: wmap = wmap * (wmap > 0.1) * m * valid; m==1 here.
            if (w > 0.1f && vi < TEX_H && ui < TEX_W) {
                int idx = vi * TEX_W + ui;
                unsafeAtomicAdd(&csum[idx * FCH + c], w * f);
                if (c == 0) unsafeAtomicAdd(&wsum[idx], w);
            }
        }
    }
}

// Normalize texture and broadcast to 8 identical batch copies.
__global__ __launch_bounds__(256) void finalize_kernel(
    const float* __restrict__ wsum,
    const float* __restrict__ csum,
    float* __restrict__ out)
{
    int t = blockIdx.x * 256 + threadIdx.x;   // texel index
    if (t >= NTEX) return;

    float w = wsum[t];
    // tex = (csum * (wsum > 0.01)) / (wsum + 0.001); csum==0 when w==0.
    float s = (w > 0.01f) ? (1.0f / (w + 0.001f)) : 0.0f;

    const float4* cs = (const float4*)(csum + (size_t)t * FCH);
    float4 a = cs[0], b = cs[1], c2 = cs[2], d = cs[3];
    a.x *= s; a.y *= s; a.z *= s; a.w *= s;
    b.x *= s; b.y *= s; b.z *= s; b.w *= s;
    c2.x *= s; c2.y *= s; c2.z *= s; c2.w *= s;
    d.x *= s; d.y *= s; d.z *= s; d.w *= s;

    #pragma unroll
    for (int bb = 0; bb < 8; ++bb) {
        float4* o = (float4*)(out + (size_t)bb * NTEX * FCH + (size_t)t * FCH);
        o[0] = a; o[1] = b; o[2] = c2; o[3] = d;
    }
}

extern "C" void kernel_launch(void* const* d_in, const int* in_sizes, int n_in,
                              void* d_out, int out_size, void* d_ws, size_t ws_size,
                              hipStream_t stream) {
    const float* f_map  = (const float*)d_in[0];
    const float* uv_map = (const float*)d_in[1];
    const float* mask   = (const float*)d_in[2];
    float* out  = (float*)d_out;

    float* wsum = (float*)d_ws;           // [NTEX]
    float* csum = wsum + NTEX;            // [NTEX * FCH]

    hipMemsetAsync(d_ws, 0, (size_t)NTEX * (FCH + 1) * sizeof(float), stream);

    int total_threads = NPIX * 16;
    splat_kernel<<<total_threads / 256, 256, 0, stream>>>(f_map, uv_map, mask, wsum, csum);

    finalize_kernel<<<NTEX / 256, 256, 0, stream>>>(wsum, csum, out);
}